// Round 2
// baseline (1546.301 us; speedup 1.0000x reference)
//
#include <hip/hip_runtime.h>
#include <cstdint>
#include <cstddef>

// ---------------------------------------------------------------------------
// WeightedTemporalSelfAttention on MI355X.
//   out = softmax((xWq (xWk)^T + chan_bias)/sqrt(2048)) @ (xWv) + b_ch + b_t[0] + PE(0)
// Precision: softmax near-one-hot -> q,k,QK^T use split-fp16 (3 MFMA passes).
// R2: chunk-major LDS layout (kills the 8-way bank conflict of row-major
//     64B-stride tiles), occupancy 4/6 blocks/CU, fused q|k GEMM, dense attn.
// ---------------------------------------------------------------------------

using h8    = __attribute__((ext_vector_type(8))) _Float16;
using h4    = __attribute__((ext_vector_type(4))) _Float16;
using f32x4 = __attribute__((ext_vector_type(4))) float;

__device__ __forceinline__ void gll16(const void* g, void* l) {
  __builtin_amdgcn_global_load_lds(
      (const __attribute__((address_space(1))) uint32_t*)g,
      (__attribute__((address_space(3))) uint32_t*)l, 16, 0, 0);
}

// ---------------- elementwise split: fp32 -> fp16 hi + fp16 lo --------------
__global__ __launch_bounds__(256) void split_x_kernel(
    const float* __restrict__ X, _Float16* __restrict__ hi,
    _Float16* __restrict__ lo, int n4)
{
  int i = blockIdx.x * 256 + threadIdx.x;
  if (i >= n4) return;
  float4 v = ((const float4*)X)[i];
  float a[4] = {v.x, v.y, v.z, v.w};
  h4 hh, ll;
#pragma unroll
  for (int e = 0; e < 4; ++e) {
    _Float16 h = (_Float16)a[e];
    hh[e] = h;
    ll[e] = (_Float16)(a[e] - (float)h);
  }
  ((h4*)hi)[i] = hh;
  ((h4*)lo)[i] = ll;
}

// ------------- transpose + split: W[k][n] fp32 -> T{hi,lo}[n][k] fp16 -------
__global__ __launch_bounds__(256) void transpose_split_w(
    const float* __restrict__ W, _Float16* __restrict__ Thi,
    _Float16* __restrict__ Tlo, int D, int writeLo)
{
  __shared__ float t[32][33];
  int n0 = blockIdx.x * 32;
  int k0 = blockIdx.y * 32;
  int tx = threadIdx.x & 31;
  int ty = threadIdx.x >> 5;  // 0..7
  for (int j = ty; j < 32; j += 8)
    t[j][tx] = W[(size_t)(k0 + j) * D + n0 + tx];
  __syncthreads();
  for (int j = ty; j < 32; j += 8) {
    float v = t[tx][j];                          // W[k0+tx][n0+j]
    size_t o = (size_t)(n0 + j) * D + k0 + tx;   // T[n][k]
    _Float16 h = (_Float16)v;
    Thi[o] = h;
    if (writeLo) Tlo[o] = (_Float16)(v - (float)h);
  }
}

// ---------------------------- tiled MFMA GEMM ------------------------------
// C[M,N] = A[M,K] * Bt[N,K]^T   (both operands row-major with K contiguous)
// 128x128 tile, BK=32, 256 threads = 4 waves (2x2), wave = 64x64 = 4x4 frags.
// LDS tile layout is CHUNK-MAJOR: slot(r,j) = j*128 + r  (slot = 16B),
// so fragment reads are 16 consecutive 16B slots per quarter-group ->
// 2-way bank aliasing only (free, m136). Staging source indices permuted
// to match (gll16 dest is fixed wave-base + lane*16).
// SPLIT: acc += Ahi*Bhi + Ahi*Blo + Alo*Bhi (3 MFMA per frag pair)
constexpr int EPI_QK = 0;   // write C as fp16 hi/lo pair (row-major, ldc)
constexpr int EPI_VT = 1;   // write C^T as fp16 (oh1[col*ldt + row])
constexpr int EPI_S  = 2;   // write C fp32 (row-major, ldc)
constexpr int EPI_CTX = 3;  // out = C + c1 + c2 + PE(odd cols +1), fp32

template<int EPI, bool SPLIT>
__global__ __launch_bounds__(256, SPLIT ? 4 : 6) void gemm_bt(
    const _Float16* __restrict__ A, const _Float16* __restrict__ Al,
    const _Float16* __restrict__ B, const _Float16* __restrict__ Bl,
    int K, int lda, int ldb, int ldc, int ldt,
    float* __restrict__ of32, _Float16* __restrict__ oh1,
    _Float16* __restrict__ oh2,
    const float* __restrict__ c1, const float* __restrict__ c2)
{
  __shared__ __align__(16) _Float16 sA [128 * 32];
  __shared__ __align__(16) _Float16 sB [128 * 32];
  __shared__ __align__(16) _Float16 sAl[SPLIT ? 128 * 32 : 8];
  __shared__ __align__(16) _Float16 sBl[SPLIT ? 128 * 32 : 8];

  const int tid  = threadIdx.x;
  const int lane = tid & 63;
  const int wave = tid >> 6;
  const int wm = wave >> 1, wn = wave & 1;
  const int m0 = blockIdx.y * 128, n0 = blockIdx.x * 128;

  // staging: slot s = issue*256 + wave*64 + lane; layout slot(r,j) = j*128+r
  //   issue 0: s0 in [0,256) -> row = s0&127, chunk j0 = s0>>7 (0/1)
  //   issue 1: s0+256        -> same row,    chunk j0+2
  const int s0 = wave * 64 + lane;
  const int r  = s0 & 127;
  const int j0 = s0 >> 7;
  const size_t lo0 = (size_t)wave * 1024;   // LDS byte base, issue 0
  const size_t lo1 = lo0 + 4096;            // issue 1 (slots +256)

  const _Float16* gA0 = A + (size_t)(m0 + r) * lda + j0 * 8;
  const _Float16* gA1 = gA0 + 16;
  const _Float16* gB0 = B + (size_t)(n0 + r) * ldb + j0 * 8;
  const _Float16* gB1 = gB0 + 16;
  const _Float16* gAl0 = Al ? Al + (size_t)(m0 + r) * lda + j0 * 8 : nullptr;
  const _Float16* gBl0 = Bl ? Bl + (size_t)(n0 + r) * ldb + j0 * 8 : nullptr;

  f32x4 acc[4][4];
#pragma unroll
  for (int i = 0; i < 4; ++i)
#pragma unroll
    for (int j = 0; j < 4; ++j) acc[i][j] = (f32x4){0.f, 0.f, 0.f, 0.f};

  const int fr = lane & 15;   // fragment row within 16-tile
  const int jc = lane >> 4;   // k-chunk 0..3 (8 halves each)

  for (int k0 = 0; k0 < K; k0 += 32) {
    gll16(gA0 + k0, (char*)sA + lo0);
    gll16(gA1 + k0, (char*)sA + lo1);
    gll16(gB0 + k0, (char*)sB + lo0);
    gll16(gB1 + k0, (char*)sB + lo1);
    if constexpr (SPLIT) {
      gll16(gAl0 + k0, (char*)sAl + lo0);
      gll16(gAl0 + 16 + k0, (char*)sAl + lo1);
      gll16(gBl0 + k0, (char*)sBl + lo0);
      gll16(gBl0 + 16 + k0, (char*)sBl + lo1);
    }
    __syncthreads();

    h8 af[4], bf[4], afl[4], bfl[4];
#pragma unroll
    for (int mi = 0; mi < 4; ++mi)
      af[mi] = *(const h8*)&sA[jc * 1024 + (wm * 64 + mi * 16 + fr) * 8];
#pragma unroll
    for (int ni = 0; ni < 4; ++ni)
      bf[ni] = *(const h8*)&sB[jc * 1024 + (wn * 64 + ni * 16 + fr) * 8];
    if constexpr (SPLIT) {
#pragma unroll
      for (int mi = 0; mi < 4; ++mi)
        afl[mi] = *(const h8*)&sAl[jc * 1024 + (wm * 64 + mi * 16 + fr) * 8];
#pragma unroll
      for (int ni = 0; ni < 4; ++ni)
        bfl[ni] = *(const h8*)&sBl[jc * 1024 + (wn * 64 + ni * 16 + fr) * 8];
    }

#pragma unroll
    for (int mi = 0; mi < 4; ++mi)
#pragma unroll
      for (int ni = 0; ni < 4; ++ni) {
        acc[mi][ni] = __builtin_amdgcn_mfma_f32_16x16x32_f16(
            af[mi], bf[ni], acc[mi][ni], 0, 0, 0);
        if constexpr (SPLIT) {
          acc[mi][ni] = __builtin_amdgcn_mfma_f32_16x16x32_f16(
              af[mi], bfl[ni], acc[mi][ni], 0, 0, 0);
          acc[mi][ni] = __builtin_amdgcn_mfma_f32_16x16x32_f16(
              afl[mi], bf[ni], acc[mi][ni], 0, 0, 0);
        }
      }
    __syncthreads();
  }

  // C/D frag: col = lane&15, row = (lane>>4)*4 + reg   [m89/m91 verified]
  const int drow = (lane >> 4) * 4;
  const int dcol = lane & 15;
#pragma unroll
  for (int mi = 0; mi < 4; ++mi) {
#pragma unroll
    for (int ni = 0; ni < 4; ++ni) {
      const int row = m0 + wm * 64 + mi * 16 + drow;
      const int col = n0 + wn * 64 + ni * 16 + dcol;
      f32x4 v = acc[mi][ni];
      if constexpr (EPI == EPI_S) {
#pragma unroll
        for (int rr = 0; rr < 4; ++rr)
          of32[(size_t)(row + rr) * ldc + col] = v[rr];
      } else if constexpr (EPI == EPI_QK) {
#pragma unroll
        for (int rr = 0; rr < 4; ++rr) {
          float x = v[rr];
          _Float16 hh = (_Float16)x;
          size_t o = (size_t)(row + rr) * ldc + col;
          oh1[o] = hh;
          oh2[o] = (_Float16)(x - (float)hh);
        }
      } else if constexpr (EPI == EPI_VT) {
        h4 hh;
#pragma unroll
        for (int rr = 0; rr < 4; ++rr) hh[rr] = (_Float16)v[rr];
        *(h4*)&oh1[(size_t)col * ldt + row] = hh;
      } else {  // EPI_CTX
#pragma unroll
        for (int rr = 0; rr < 4; ++rr) {
          size_t o = (size_t)(row + rr) * ldc + col;
          of32[o] = v[rr] + c1[o] + c2[o] + ((col & 1) ? 1.0f : 0.0f);
        }
      }
    }
  }
}

// ------------- row softmax with channel bias; fp32 S -> fp16 attn ----------
__global__ __launch_bounds__(256) void softmax_bias_kernel(
    const float* __restrict__ S, _Float16* __restrict__ attn, int N)
{
  const float scale = 0.022097086912079608f;  // 1/sqrt(2048)
  const int row = blockIdx.x;
  const float* rp = S + (size_t)row * N;
  const int cblk = row & ~63;  // channel block start (CW=64)
  const int tid = threadIdx.x;

  float vals[16];
  float mx = -3.0e38f;
#pragma unroll
  for (int it = 0; it < 4; ++it) {
    int base = (it * 256 + tid) * 4;
    float4 v = *(const float4*)(rp + base);
    float a[4] = {v.x, v.y, v.z, v.w};
#pragma unroll
    for (int e = 0; e < 4; ++e) {
      int col = base + e;
      float s = a[e];
      if ((col & ~63) == cblk) s += 1.0f;  // bias BEFORE scaling (reference)
      s *= scale;
      vals[it * 4 + e] = s;
      mx = fmaxf(mx, s);
    }
  }
  __shared__ float red[8];
#pragma unroll
  for (int m = 32; m; m >>= 1) mx = fmaxf(mx, __shfl_xor(mx, m, 64));
  if ((tid & 63) == 0) red[tid >> 6] = mx;
  __syncthreads();
  mx = fmaxf(fmaxf(red[0], red[1]), fmaxf(red[2], red[3]));

  float sum = 0.f;
#pragma unroll
  for (int i = 0; i < 16; ++i) {
    float e = __expf(vals[i] - mx);
    vals[i] = e;
    sum += e;
  }
#pragma unroll
  for (int m = 32; m; m >>= 1) sum += __shfl_xor(sum, m, 64);
  if ((tid & 63) == 0) red[4 + (tid >> 6)] = sum;
  __syncthreads();
  sum = red[4] + red[5] + red[6] + red[7];
  float inv = 1.0f / sum;

  _Float16* op = attn + (size_t)row * N;
#pragma unroll
  for (int it = 0; it < 4; ++it) {
    int base = (it * 256 + tid) * 4;
    h4 hh;
#pragma unroll
    for (int e = 0; e < 4; ++e) hh[e] = (_Float16)(vals[it * 4 + e] * inv);
    *(h4*)(op + base) = hh;
  }
}

// ---------------------------------------------------------------------------
extern "C" void kernel_launch(void* const* d_in, const int* in_sizes, int n_in,
                              void* d_out, int out_size, void* d_ws,
                              size_t ws_size, hipStream_t stream)
{
  (void)in_sizes; (void)n_in; (void)out_size; (void)ws_size;
  const float* x   = (const float*)d_in[0];  // [4096,2048]
  const float* Wq  = (const float*)d_in[1];  // [2048,2048]
  const float* Wk  = (const float*)d_in[2];
  const float* Wv  = (const float*)d_in[3];
  const float* bch = (const float*)d_in[4];  // [4096,2048]
  const float* bt0 = (const float*)d_in[5];  // b_t[0]
  float* out = (float*)d_out;

  char* ws = (char*)d_ws;
  // Phase A: [0,67.1M) = xhi,xlo,wqkh,wqkl ; wvh ; vT ; qkh ; qkl
  // Phase B: S (67.1M) aliases [0,67.1M) after step 4; attn aliases qkh.
  const size_t O_XHI  = 0;                    // 16.8M, dead after vT gemm
  const size_t O_XLO  = 16777216;             // 16.8M
  const size_t O_WQKH = 33554432;             // 16.8M ([Wq|Wk]^T hi)
  const size_t O_WQKL = 50331648;             // 16.8M, region ends 67108864
  const size_t O_WVH  = 67108864;             //  8.4M, dead after vT gemm
  const size_t O_VT   = 75497472;             // 16.8M, live to end
  const size_t O_QKH  = 92274688;             // 33.55M (q|k hi, ld 4096)
  const size_t O_QKL  = 125829120;            // 33.55M, ends 159383552
  const size_t O_S    = 0;                    // 67.1M fp32 (alias phase A)
  const size_t O_ATTN = O_QKH;                // 33.55M fp16 (alias dead q|k)

  _Float16* xhi  = (_Float16*)(ws + O_XHI);
  _Float16* xlo  = (_Float16*)(ws + O_XLO);
  _Float16* wqkh = (_Float16*)(ws + O_WQKH);
  _Float16* wqkl = (_Float16*)(ws + O_WQKL);
  _Float16* wvh  = (_Float16*)(ws + O_WVH);
  _Float16* vT   = (_Float16*)(ws + O_VT);
  _Float16* qkh  = (_Float16*)(ws + O_QKH);
  _Float16* qkl  = (_Float16*)(ws + O_QKL);
  float*    S    = (float*)(ws + O_S);
  _Float16* attn = (_Float16*)(ws + O_ATTN);

  // 1) split x
  split_x_kernel<<<2097152 / 256, 256, 0, stream>>>(x, xhi, xlo, 2097152);
  // 2) transpose+split weights; Wq and Wk stacked -> B = [Wq|Wk]^T (4096 rows)
  dim3 tg(64, 64);
  transpose_split_w<<<tg, 256, 0, stream>>>(Wq, wqkh, wqkl, 2048, 1);
  transpose_split_w<<<tg, 256, 0, stream>>>(Wk, wqkh + 4194304, wqkl + 4194304, 2048, 1);
  transpose_split_w<<<tg, 256, 0, stream>>>(Wv, wvh, nullptr, 2048, 0);

  // 3) [q|k] = x @ [Wq|Wk]  (split, fused, hi/lo out, ldc=4096)
  dim3 gqk(4096 / 128, 4096 / 128);
  gemm_bt<EPI_QK, true><<<gqk, 256, 0, stream>>>(
      xhi, xlo, wqkh, wqkl, 2048, 2048, 2048, 4096, 0,
      nullptr, qkh, qkl, nullptr, nullptr);
  // 4) vT = (x@Wv)^T  (plain fp16, transposed write)
  dim3 gv(2048 / 128, 4096 / 128);
  gemm_bt<EPI_VT, false><<<gv, 256, 0, stream>>>(
      xhi, nullptr, wvh, nullptr, 2048, 2048, 2048, 0, 4096,
      nullptr, vT, nullptr, nullptr, nullptr);

  // 5) S = q@k^T (split; q = qk cols 0..2047, k = cols 2048..4095)
  dim3 gs(4096 / 128, 4096 / 128);
  gemm_bt<EPI_S, true><<<gs, 256, 0, stream>>>(
      qkh, qkl, qkh + 2048, qkl + 2048, 2048, 4096, 4096, 4096, 0,
      S, nullptr, nullptr, nullptr, nullptr);

  // 6) softmax((S + chan_bias)/sqrt(d)) -> dense fp16 attn
  softmax_bias_kernel<<<4096, 256, 0, stream>>>(S, attn, 4096);

  // 7) out = attn@v + b_channel + b_t[0] + PE(0)
  dim3 gc(2048 / 128, 4096 / 128);
  gemm_bt<EPI_CTX, false><<<gc, 256, 0, stream>>>(
      attn, nullptr, vT, nullptr, 4096, 4096, 4096, 2048, 0,
      out, nullptr, nullptr, bch, bt0);
}

// Round 3
// 1146.216 us; speedup vs baseline: 1.3490x; 1.3490x over previous
//
#include <hip/hip_runtime.h>
#include <cstdint>
#include <cstddef>

// ---------------------------------------------------------------------------
// WeightedTemporalSelfAttention on MI355X.
//   out = softmax((xWq (xWk)^T + chan_bias)/sqrt(2048)) @ (xWv) + b_ch + b_t[0] + PE(0)
// Precision: softmax near-one-hot -> q,k,QK^T use split-fp16 (3 MFMA passes).
// R2: chunk-major LDS layout -> SQ_LDS_BANK_CONFLICT == 0 (verified).
// R3: fix R2's register-spill disaster: launch_bounds (256,2)/(256,3).
//     gfx950 unified VGPR/AGPR file: acc[4][4] = 64 regs counts against the
//     bound; (256,6) forced VGPR=40 -> acc spilled to scratch (WRITE_SIZE
//     323MB on a 33.5MB-output GEMM, MfmaUtil 6%).
// ---------------------------------------------------------------------------

using h8    = __attribute__((ext_vector_type(8))) _Float16;
using h4    = __attribute__((ext_vector_type(4))) _Float16;
using f32x4 = __attribute__((ext_vector_type(4))) float;

__device__ __forceinline__ void gll16(const void* g, void* l) {
  __builtin_amdgcn_global_load_lds(
      (const __attribute__((address_space(1))) uint32_t*)g,
      (__attribute__((address_space(3))) uint32_t*)l, 16, 0, 0);
}

// ---------------- elementwise split: fp32 -> fp16 hi + fp16 lo --------------
__global__ __launch_bounds__(256) void split_x_kernel(
    const float* __restrict__ X, _Float16* __restrict__ hi,
    _Float16* __restrict__ lo, int n4)
{
  int i = blockIdx.x * 256 + threadIdx.x;
  if (i >= n4) return;
  float4 v = ((const float4*)X)[i];
  float a[4] = {v.x, v.y, v.z, v.w};
  h4 hh, ll;
#pragma unroll
  for (int e = 0; e < 4; ++e) {
    _Float16 h = (_Float16)a[e];
    hh[e] = h;
    ll[e] = (_Float16)(a[e] - (float)h);
  }
  ((h4*)hi)[i] = hh;
  ((h4*)lo)[i] = ll;
}

// ------------- transpose + split: W[k][n] fp32 -> T{hi,lo}[n][k] fp16 -------
__global__ __launch_bounds__(256) void transpose_split_w(
    const float* __restrict__ W, _Float16* __restrict__ Thi,
    _Float16* __restrict__ Tlo, int D, int writeLo)
{
  __shared__ float t[32][33];
  int n0 = blockIdx.x * 32;
  int k0 = blockIdx.y * 32;
  int tx = threadIdx.x & 31;
  int ty = threadIdx.x >> 5;  // 0..7
  for (int j = ty; j < 32; j += 8)
    t[j][tx] = W[(size_t)(k0 + j) * D + n0 + tx];
  __syncthreads();
  for (int j = ty; j < 32; j += 8) {
    float v = t[tx][j];                          // W[k0+tx][n0+j]
    size_t o = (size_t)(n0 + j) * D + k0 + tx;   // T[n][k]
    _Float16 h = (_Float16)v;
    Thi[o] = h;
    if (writeLo) Tlo[o] = (_Float16)(v - (float)h);
  }
}

// ---------------------------- tiled MFMA GEMM ------------------------------
// C[M,N] = A[M,K] * Bt[N,K]^T   (both operands row-major with K contiguous)
// 128x128 tile, BK=32, 256 threads = 4 waves (2x2), wave = 64x64 = 4x4 frags.
// LDS tile layout is CHUNK-MAJOR: slot(r,j) = j*128 + r  (slot = 16B) ->
// fragment reads are 16 consecutive 16B slots per quarter-group -> 2-way
// bank aliasing only (free). Verified: SQ_LDS_BANK_CONFLICT == 0.
// SPLIT: acc += Ahi*Bhi + Ahi*Blo + Alo*Bhi (3 MFMA per frag pair)
constexpr int EPI_QK = 0;   // write C as fp16 hi/lo pair (row-major, ldc)
constexpr int EPI_VT = 1;   // write C^T as fp16 (oh1[col*ldt + row])
constexpr int EPI_S  = 2;   // write C fp32 (row-major, ldc)
constexpr int EPI_CTX = 3;  // out = C + c1 + c2 + PE(odd cols +1), fp32

template<int EPI, bool SPLIT>
__global__ __launch_bounds__(256, SPLIT ? 2 : 3) void gemm_bt(
    const _Float16* __restrict__ A, const _Float16* __restrict__ Al,
    const _Float16* __restrict__ B, const _Float16* __restrict__ Bl,
    int K, int lda, int ldb, int ldc, int ldt,
    float* __restrict__ of32, _Float16* __restrict__ oh1,
    _Float16* __restrict__ oh2,
    const float* __restrict__ c1, const float* __restrict__ c2)
{
  __shared__ __align__(16) _Float16 sA [128 * 32];
  __shared__ __align__(16) _Float16 sB [128 * 32];
  __shared__ __align__(16) _Float16 sAl[SPLIT ? 128 * 32 : 8];
  __shared__ __align__(16) _Float16 sBl[SPLIT ? 128 * 32 : 8];

  const int tid  = threadIdx.x;
  const int lane = tid & 63;
  const int wave = tid >> 6;
  const int wm = wave >> 1, wn = wave & 1;
  const int m0 = blockIdx.y * 128, n0 = blockIdx.x * 128;

  // staging: slot s = issue*256 + wave*64 + lane; layout slot(r,j) = j*128+r
  const int s0 = wave * 64 + lane;
  const int r  = s0 & 127;
  const int j0 = s0 >> 7;
  const size_t lo0 = (size_t)wave * 1024;   // LDS byte base, issue 0
  const size_t lo1 = lo0 + 4096;            // issue 1 (slots +256)

  const _Float16* gA0 = A + (size_t)(m0 + r) * lda + j0 * 8;
  const _Float16* gA1 = gA0 + 16;
  const _Float16* gB0 = B + (size_t)(n0 + r) * ldb + j0 * 8;
  const _Float16* gB1 = gB0 + 16;
  const _Float16* gAl0 = Al ? Al + (size_t)(m0 + r) * lda + j0 * 8 : nullptr;
  const _Float16* gBl0 = Bl ? Bl + (size_t)(n0 + r) * ldb + j0 * 8 : nullptr;

  f32x4 acc[4][4];
#pragma unroll
  for (int i = 0; i < 4; ++i)
#pragma unroll
    for (int j = 0; j < 4; ++j) acc[i][j] = (f32x4){0.f, 0.f, 0.f, 0.f};

  const int fr = lane & 15;   // fragment row within 16-tile
  const int jc = lane >> 4;   // k-chunk 0..3 (8 halves each)

  for (int k0 = 0; k0 < K; k0 += 32) {
    gll16(gA0 + k0, (char*)sA + lo0);
    gll16(gA1 + k0, (char*)sA + lo1);
    gll16(gB0 + k0, (char*)sB + lo0);
    gll16(gB1 + k0, (char*)sB + lo1);
    if constexpr (SPLIT) {
      gll16(gAl0 + k0, (char*)sAl + lo0);
      gll16(gAl0 + 16 + k0, (char*)sAl + lo1);
      gll16(gBl0 + k0, (char*)sBl + lo0);
      gll16(gBl0 + 16 + k0, (char*)sBl + lo1);
    }
    __syncthreads();

    h8 af[4], bf[4], afl[4], bfl[4];
#pragma unroll
    for (int mi = 0; mi < 4; ++mi)
      af[mi] = *(const h8*)&sA[jc * 1024 + (wm * 64 + mi * 16 + fr) * 8];
#pragma unroll
    for (int ni = 0; ni < 4; ++ni)
      bf[ni] = *(const h8*)&sB[jc * 1024 + (wn * 64 + ni * 16 + fr) * 8];
    if constexpr (SPLIT) {
#pragma unroll
      for (int mi = 0; mi < 4; ++mi)
        afl[mi] = *(const h8*)&sAl[jc * 1024 + (wm * 64 + mi * 16 + fr) * 8];
#pragma unroll
      for (int ni = 0; ni < 4; ++ni)
        bfl[ni] = *(const h8*)&sBl[jc * 1024 + (wn * 64 + ni * 16 + fr) * 8];
    }

#pragma unroll
    for (int mi = 0; mi < 4; ++mi)
#pragma unroll
      for (int ni = 0; ni < 4; ++ni) {
        acc[mi][ni] = __builtin_amdgcn_mfma_f32_16x16x32_f16(
            af[mi], bf[ni], acc[mi][ni], 0, 0, 0);
        if constexpr (SPLIT) {
          acc[mi][ni] = __builtin_amdgcn_mfma_f32_16x16x32_f16(
              af[mi], bfl[ni], acc[mi][ni], 0, 0, 0);
          acc[mi][ni] = __builtin_amdgcn_mfma_f32_16x16x32_f16(
              afl[mi], bf[ni], acc[mi][ni], 0, 0, 0);
        }
      }
    __syncthreads();
  }

  // C/D frag: col = lane&15, row = (lane>>4)*4 + reg   [m89/m91 verified]
  const int drow = (lane >> 4) * 4;
  const int dcol = lane & 15;
#pragma unroll
  for (int mi = 0; mi < 4; ++mi) {
#pragma unroll
    for (int ni = 0; ni < 4; ++ni) {
      const int row = m0 + wm * 64 + mi * 16 + drow;
      const int col = n0 + wn * 64 + ni * 16 + dcol;
      f32x4 v = acc[mi][ni];
      if constexpr (EPI == EPI_S) {
#pragma unroll
        for (int rr = 0; rr < 4; ++rr)
          of32[(size_t)(row + rr) * ldc + col] = v[rr];
      } else if constexpr (EPI == EPI_QK) {
#pragma unroll
        for (int rr = 0; rr < 4; ++rr) {
          float x = v[rr];
          _Float16 hh = (_Float16)x;
          size_t o = (size_t)(row + rr) * ldc + col;
          oh1[o] = hh;
          oh2[o] = (_Float16)(x - (float)hh);
        }
      } else if constexpr (EPI == EPI_VT) {
        h4 hh;
#pragma unroll
        for (int rr = 0; rr < 4; ++rr) hh[rr] = (_Float16)v[rr];
        *(h4*)&oh1[(size_t)col * ldt + row] = hh;
      } else {  // EPI_CTX
#pragma unroll
        for (int rr = 0; rr < 4; ++rr) {
          size_t o = (size_t)(row + rr) * ldc + col;
          of32[o] = v[rr] + c1[o] + c2[o] + ((col & 1) ? 1.0f : 0.0f);
        }
      }
    }
  }
}

// ------------- row softmax with channel bias; fp32 S -> fp16 attn ----------
__global__ __launch_bounds__(256) void softmax_bias_kernel(
    const float* __restrict__ S, _Float16* __restrict__ attn, int N)
{
  const float scale = 0.022097086912079608f;  // 1/sqrt(2048)
  const int row = blockIdx.x;
  const float* rp = S + (size_t)row * N;
  const int cblk = row & ~63;  // channel block start (CW=64)
  const int tid = threadIdx.x;

  float vals[16];
  float mx = -3.0e38f;
#pragma unroll
  for (int it = 0; it < 4; ++it) {
    int base = (it * 256 + tid) * 4;
    float4 v = *(const float4*)(rp + base);
    float a[4] = {v.x, v.y, v.z, v.w};
#pragma unroll
    for (int e = 0; e < 4; ++e) {
      int col = base + e;
      float s = a[e];
      if ((col & ~63) == cblk) s += 1.0f;  // bias BEFORE scaling (reference)
      s *= scale;
      vals[it * 4 + e] = s;
      mx = fmaxf(mx, s);
    }
  }
  __shared__ float red[8];
#pragma unroll
  for (int m = 32; m; m >>= 1) mx = fmaxf(mx, __shfl_xor(mx, m, 64));
  if ((tid & 63) == 0) red[tid >> 6] = mx;
  __syncthreads();
  mx = fmaxf(fmaxf(red[0], red[1]), fmaxf(red[2], red[3]));

  float sum = 0.f;
#pragma unroll
  for (int i = 0; i < 16; ++i) {
    float e = __expf(vals[i] - mx);
    vals[i] = e;
    sum += e;
  }
#pragma unroll
  for (int m = 32; m; m >>= 1) sum += __shfl_xor(sum, m, 64);
  if ((tid & 63) == 0) red[4 + (tid >> 6)] = sum;
  __syncthreads();
  sum = red[4] + red[5] + red[6] + red[7];
  float inv = 1.0f / sum;

  _Float16* op = attn + (size_t)row * N;
#pragma unroll
  for (int it = 0; it < 4; ++it) {
    int base = (it * 256 + tid) * 4;
    h4 hh;
#pragma unroll
    for (int e = 0; e < 4; ++e) hh[e] = (_Float16)(vals[it * 4 + e] * inv);
    *(h4*)(op + base) = hh;
  }
}

// ---------------------------------------------------------------------------
extern "C" void kernel_launch(void* const* d_in, const int* in_sizes, int n_in,
                              void* d_out, int out_size, void* d_ws,
                              size_t ws_size, hipStream_t stream)
{
  (void)in_sizes; (void)n_in; (void)out_size; (void)ws_size;
  const float* x   = (const float*)d_in[0];  // [4096,2048]
  const float* Wq  = (const float*)d_in[1];  // [2048,2048]
  const float* Wk  = (const float*)d_in[2];
  const float* Wv  = (const float*)d_in[3];
  const float* bch = (const float*)d_in[4];  // [4096,2048]
  const float* bt0 = (const float*)d_in[5];  // b_t[0]
  float* out = (float*)d_out;

  char* ws = (char*)d_ws;
  // Phase A: [0,67.1M) = xhi,xlo,wqkh,wqkl ; wvh ; vT ; qkh ; qkl
  // Phase B: S (67.1M) aliases [0,67.1M) after step 4; attn aliases qkh.
  const size_t O_XHI  = 0;                    // 16.8M, dead after vT gemm
  const size_t O_XLO  = 16777216;             // 16.8M
  const size_t O_WQKH = 33554432;             // 16.8M ([Wq|Wk]^T hi)
  const size_t O_WQKL = 50331648;             // 16.8M, region ends 67108864
  const size_t O_WVH  = 67108864;             //  8.4M, dead after vT gemm
  const size_t O_VT   = 75497472;             // 16.8M, live to end
  const size_t O_QKH  = 92274688;             // 33.55M (q|k hi, ld 4096)
  const size_t O_QKL  = 125829120;            // 33.55M, ends 159383552
  const size_t O_S    = 0;                    // 67.1M fp32 (alias phase A)
  const size_t O_ATTN = O_QKH;                // 33.55M fp16 (alias dead q|k)

  _Float16* xhi  = (_Float16*)(ws + O_XHI);
  _Float16* xlo  = (_Float16*)(ws + O_XLO);
  _Float16* wqkh = (_Float16*)(ws + O_WQKH);
  _Float16* wqkl = (_Float16*)(ws + O_WQKL);
  _Float16* wvh  = (_Float16*)(ws + O_WVH);
  _Float16* vT   = (_Float16*)(ws + O_VT);
  _Float16* qkh  = (_Float16*)(ws + O_QKH);
  _Float16* qkl  = (_Float16*)(ws + O_QKL);
  float*    S    = (float*)(ws + O_S);
  _Float16* attn = (_Float16*)(ws + O_ATTN);

  // 1) split x
  split_x_kernel<<<2097152 / 256, 256, 0, stream>>>(x, xhi, xlo, 2097152);
  // 2) transpose+split weights; Wq and Wk stacked -> B = [Wq|Wk]^T (4096 rows)
  dim3 tg(64, 64);
  transpose_split_w<<<tg, 256, 0, stream>>>(Wq, wqkh, wqkl, 2048, 1);
  transpose_split_w<<<tg, 256, 0, stream>>>(Wk, wqkh + 4194304, wqkl + 4194304, 2048, 1);
  transpose_split_w<<<tg, 256, 0, stream>>>(Wv, wvh, nullptr, 2048, 0);

  // 3) [q|k] = x @ [Wq|Wk]  (split, fused, hi/lo out, ldc=4096)
  dim3 gqk(4096 / 128, 4096 / 128);
  gemm_bt<EPI_QK, true><<<gqk, 256, 0, stream>>>(
      xhi, xlo, wqkh, wqkl, 2048, 2048, 2048, 4096, 0,
      nullptr, qkh, qkl, nullptr, nullptr);
  // 4) vT = (x@Wv)^T  (plain fp16, transposed write)
  dim3 gv(2048 / 128, 4096 / 128);
  gemm_bt<EPI_VT, false><<<gv, 256, 0, stream>>>(
      xhi, nullptr, wvh, nullptr, 2048, 2048, 2048, 0, 4096,
      nullptr, vT, nullptr, nullptr, nullptr);

  // 5) S = q@k^T (split; q = qk cols 0..2047, k = cols 2048..4095)
  dim3 gs(4096 / 128, 4096 / 128);
  gemm_bt<EPI_S, true><<<gs, 256, 0, stream>>>(
      qkh, qkl, qkh + 2048, qkl + 2048, 2048, 4096, 4096, 4096, 0,
      S, nullptr, nullptr, nullptr, nullptr);

  // 6) softmax((S + chan_bias)/sqrt(d)) -> dense fp16 attn
  softmax_bias_kernel<<<4096, 256, 0, stream>>>(S, attn, 4096);

  // 7) out = attn@v + b_channel + b_t[0] + PE(0)
  dim3 gc(2048 / 128, 4096 / 128);
  gemm_bt<EPI_CTX, false><<<gc, 256, 0, stream>>>(
      attn, nullptr, vT, nullptr, 4096, 4096, 4096, 2048, 0,
      out, nullptr, nullptr, bch, bt0);
}

// Round 4
// 1123.736 us; speedup vs baseline: 1.3760x; 1.0200x over previous
//
#include <hip/hip_runtime.h>
#include <cstdint>
#include <cstddef>

// ---------------------------------------------------------------------------
// WeightedTemporalSelfAttention on MI355X.
//   out = softmax((xWq (xWk)^T + chan_bias)/sqrt(2048)) @ (xWv) + b_ch + b_t[0] + PE(0)
// Precision: softmax near-one-hot -> q,k,QK^T use split-fp16 (3 MFMA passes).
// R3 lesson: launch_bounds must leave room for acc[4][4] (unified VGPR/AGPR).
// R4: block-local chunk-major LDS map — slot s holds A[(s>>6)*16 + (s&15)]
//     [((s>>4)&3)*8 ..]. Staging instruction (64 consecutive slots) reads
//     16 rows x 64B contiguous (R1-coalesced); fragment ds_read address is
//     16*lane-linear (zero bank conflict, R3-verified). Both fixed at once.
// ---------------------------------------------------------------------------

using h8    = __attribute__((ext_vector_type(8))) _Float16;
using h4    = __attribute__((ext_vector_type(4))) _Float16;
using f32x4 = __attribute__((ext_vector_type(4))) float;

__device__ __forceinline__ void gll16(const void* g, void* l) {
  __builtin_amdgcn_global_load_lds(
      (const __attribute__((address_space(1))) uint32_t*)g,
      (__attribute__((address_space(3))) uint32_t*)l, 16, 0, 0);
}

// ---------------- elementwise split: fp32 -> fp16 hi + fp16 lo --------------
__global__ __launch_bounds__(256) void split_x_kernel(
    const float* __restrict__ X, _Float16* __restrict__ hi,
    _Float16* __restrict__ lo, int n4)
{
  int i = blockIdx.x * 256 + threadIdx.x;
  if (i >= n4) return;
  float4 v = ((const float4*)X)[i];
  float a[4] = {v.x, v.y, v.z, v.w};
  h4 hh, ll;
#pragma unroll
  for (int e = 0; e < 4; ++e) {
    _Float16 h = (_Float16)a[e];
    hh[e] = h;
    ll[e] = (_Float16)(a[e] - (float)h);
  }
  ((h4*)hi)[i] = hh;
  ((h4*)lo)[i] = ll;
}

// ------------- transpose + split: W[k][n] fp32 -> T{hi,lo}[n][k] fp16 -------
__global__ __launch_bounds__(256) void transpose_split_w(
    const float* __restrict__ W, _Float16* __restrict__ Thi,
    _Float16* __restrict__ Tlo, int D, int writeLo)
{
  __shared__ float t[32][33];
  int n0 = blockIdx.x * 32;
  int k0 = blockIdx.y * 32;
  int tx = threadIdx.x & 31;
  int ty = threadIdx.x >> 5;  // 0..7
  for (int j = ty; j < 32; j += 8)
    t[j][tx] = W[(size_t)(k0 + j) * D + n0 + tx];
  __syncthreads();
  for (int j = ty; j < 32; j += 8) {
    float v = t[tx][j];                          // W[k0+tx][n0+j]
    size_t o = (size_t)(n0 + j) * D + k0 + tx;   // T[n][k]
    _Float16 h = (_Float16)v;
    Thi[o] = h;
    if (writeLo) Tlo[o] = (_Float16)(v - (float)h);
  }
}

// ---------------------------- tiled MFMA GEMM ------------------------------
// C[M,N] = A[M,K] * Bt[N,K]^T   (both operands row-major with K contiguous)
// 128x128 tile, BK=32, 256 threads = 4 waves (2x2), wave = 64x64 = 4x4 frags.
// LDS map (16B slots): slot s <- A[(s>>6)*16 + (s&15)][((s>>4)&3)*8 ..].
//   staging instr (wave,issue) = slots (issue*4+wave)*64 ..+63:
//     lane reads row base+(lane&15), chunk lane>>4  -> 16 x 64B segments.
//   fragment read: byte (row>>4)*1024 + jc*256 + fr*16 -> 16*lane-linear.
// SPLIT: acc += Ahi*Bhi + Ahi*Blo + Alo*Bhi (3 MFMA per frag pair)
constexpr int EPI_QK = 0;   // write C as fp16 hi/lo pair (row-major, ldc)
constexpr int EPI_VT = 1;   // write C^T as fp16 (oh1[col*ldt + row])
constexpr int EPI_S  = 2;   // write C fp32 (row-major, ldc)
constexpr int EPI_CTX = 3;  // out = C + c1 + c2 + PE(odd cols +1), fp32

template<int EPI, bool SPLIT>
__global__ __launch_bounds__(256, SPLIT ? 2 : 3) void gemm_bt(
    const _Float16* __restrict__ A, const _Float16* __restrict__ Al,
    const _Float16* __restrict__ B, const _Float16* __restrict__ Bl,
    int K, int lda, int ldb, int ldc, int ldt,
    float* __restrict__ of32, _Float16* __restrict__ oh1,
    _Float16* __restrict__ oh2,
    const float* __restrict__ c1, const float* __restrict__ c2)
{
  __shared__ __align__(16) _Float16 sA [128 * 32];
  __shared__ __align__(16) _Float16 sB [128 * 32];
  __shared__ __align__(16) _Float16 sAl[SPLIT ? 128 * 32 : 8];
  __shared__ __align__(16) _Float16 sBl[SPLIT ? 128 * 32 : 8];

  const int tid  = threadIdx.x;
  const int lane = tid & 63;
  const int wave = tid >> 6;
  const int wm = wave >> 1, wn = wave & 1;
  const int m0 = blockIdx.y * 128, n0 = blockIdx.x * 128;

  // staging source for this lane: row base + (lane&15), k-chunk lane>>4
  const int rl = lane & 15;
  const int cl = lane >> 4;
  const size_t lo0 = (size_t)wave * 1024;   // LDS bytes, issue 0 (slots w*64)
  const size_t lo1 = lo0 + 4096;            // issue 1 (slots 256 + w*64)

  const _Float16* gA0 = A + (size_t)(m0 + wave * 16 + rl) * lda + cl * 8;
  const _Float16* gB0 = B + (size_t)(n0 + wave * 16 + rl) * ldb + cl * 8;
  const _Float16* gAl0 = Al ? Al + (size_t)(m0 + wave * 16 + rl) * lda + cl * 8 : nullptr;
  const _Float16* gBl0 = Bl ? Bl + (size_t)(n0 + wave * 16 + rl) * ldb + cl * 8 : nullptr;
  const size_t dA = (size_t)64 * lda;       // issue-1 = rows +64
  const size_t dB = (size_t)64 * ldb;

  f32x4 acc[4][4];
#pragma unroll
  for (int i = 0; i < 4; ++i)
#pragma unroll
    for (int j = 0; j < 4; ++j) acc[i][j] = (f32x4){0.f, 0.f, 0.f, 0.f};

  const int fr = lane & 15;   // fragment row within 16-tile
  const int jc = lane >> 4;   // k-chunk 0..3 (8 halves each)

  for (int k0 = 0; k0 < K; k0 += 32) {
    gll16(gA0 + k0,      (char*)sA + lo0);
    gll16(gA0 + dA + k0, (char*)sA + lo1);
    gll16(gB0 + k0,      (char*)sB + lo0);
    gll16(gB0 + dB + k0, (char*)sB + lo1);
    if constexpr (SPLIT) {
      gll16(gAl0 + k0,      (char*)sAl + lo0);
      gll16(gAl0 + dA + k0, (char*)sAl + lo1);
      gll16(gBl0 + k0,      (char*)sBl + lo0);
      gll16(gBl0 + dB + k0, (char*)sBl + lo1);
    }
    __syncthreads();

    h8 af[4], bf[4], afl[4], bfl[4];
#pragma unroll
    for (int mi = 0; mi < 4; ++mi)
      af[mi] = *(const h8*)&sA[(wm * 4 + mi) * 512 + jc * 128 + fr * 8];
#pragma unroll
    for (int ni = 0; ni < 4; ++ni)
      bf[ni] = *(const h8*)&sB[(wn * 4 + ni) * 512 + jc * 128 + fr * 8];
    if constexpr (SPLIT) {
#pragma unroll
      for (int mi = 0; mi < 4; ++mi)
        afl[mi] = *(const h8*)&sAl[(wm * 4 + mi) * 512 + jc * 128 + fr * 8];
#pragma unroll
      for (int ni = 0; ni < 4; ++ni)
        bfl[ni] = *(const h8*)&sBl[(wn * 4 + ni) * 512 + jc * 128 + fr * 8];
    }

#pragma unroll
    for (int mi = 0; mi < 4; ++mi)
#pragma unroll
      for (int ni = 0; ni < 4; ++ni) {
        acc[mi][ni] = __builtin_amdgcn_mfma_f32_16x16x32_f16(
            af[mi], bf[ni], acc[mi][ni], 0, 0, 0);
        if constexpr (SPLIT) {
          acc[mi][ni] = __builtin_amdgcn_mfma_f32_16x16x32_f16(
              af[mi], bfl[ni], acc[mi][ni], 0, 0, 0);
          acc[mi][ni] = __builtin_amdgcn_mfma_f32_16x16x32_f16(
              afl[mi], bf[ni], acc[mi][ni], 0, 0, 0);
        }
      }
    __syncthreads();
  }

  // C/D frag: col = lane&15, row = (lane>>4)*4 + reg   [m89/m91 verified]
  const int drow = (lane >> 4) * 4;
  const int dcol = lane & 15;
#pragma unroll
  for (int mi = 0; mi < 4; ++mi) {
#pragma unroll
    for (int ni = 0; ni < 4; ++ni) {
      const int row = m0 + wm * 64 + mi * 16 + drow;
      const int col = n0 + wn * 64 + ni * 16 + dcol;
      f32x4 v = acc[mi][ni];
      if constexpr (EPI == EPI_S) {
#pragma unroll
        for (int rr = 0; rr < 4; ++rr)
          of32[(size_t)(row + rr) * ldc + col] = v[rr];
      } else if constexpr (EPI == EPI_QK) {
#pragma unroll
        for (int rr = 0; rr < 4; ++rr) {
          float x = v[rr];
          _Float16 hh = (_Float16)x;
          size_t o = (size_t)(row + rr) * ldc + col;
          oh1[o] = hh;
          oh2[o] = (_Float16)(x - (float)hh);
        }
      } else if constexpr (EPI == EPI_VT) {
        h4 hh;
#pragma unroll
        for (int rr = 0; rr < 4; ++rr) hh[rr] = (_Float16)v[rr];
        *(h4*)&oh1[(size_t)col * ldt + row] = hh;
      } else {  // EPI_CTX
#pragma unroll
        for (int rr = 0; rr < 4; ++rr) {
          size_t o = (size_t)(row + rr) * ldc + col;
          of32[o] = v[rr] + c1[o] + c2[o] + ((col & 1) ? 1.0f : 0.0f);
        }
      }
    }
  }
}

// ------------- row softmax with channel bias; fp32 S -> fp16 attn ----------
__global__ __launch_bounds__(256) void softmax_bias_kernel(
    const float* __restrict__ S, _Float16* __restrict__ attn, int N)
{
  const float scale = 0.022097086912079608f;  // 1/sqrt(2048)
  const int row = blockIdx.x;
  const float* rp = S + (size_t)row * N;
  const int cblk = row & ~63;  // channel block start (CW=64)
  const int tid = threadIdx.x;

  float vals[16];
  float mx = -3.0e38f;
#pragma unroll
  for (int it = 0; it < 4; ++it) {
    int base = (it * 256 + tid) * 4;
    float4 v = *(const float4*)(rp + base);
    float a[4] = {v.x, v.y, v.z, v.w};
#pragma unroll
    for (int e = 0; e < 4; ++e) {
      int col = base + e;
      float s = a[e];
      if ((col & ~63) == cblk) s += 1.0f;  // bias BEFORE scaling (reference)
      s *= scale;
      vals[it * 4 + e] = s;
      mx = fmaxf(mx, s);
    }
  }
  __shared__ float red[8];
#pragma unroll
  for (int m = 32; m; m >>= 1) mx = fmaxf(mx, __shfl_xor(mx, m, 64));
  if ((tid & 63) == 0) red[tid >> 6] = mx;
  __syncthreads();
  mx = fmaxf(fmaxf(red[0], red[1]), fmaxf(red[2], red[3]));

  float sum = 0.f;
#pragma unroll
  for (int i = 0; i < 16; ++i) {
    float e = __expf(vals[i] - mx);
    vals[i] = e;
    sum += e;
  }
#pragma unroll
  for (int m = 32; m; m >>= 1) sum += __shfl_xor(sum, m, 64);
  if ((tid & 63) == 0) red[4 + (tid >> 6)] = sum;
  __syncthreads();
  sum = red[4] + red[5] + red[6] + red[7];
  float inv = 1.0f / sum;

  _Float16* op = attn + (size_t)row * N;
#pragma unroll
  for (int it = 0; it < 4; ++it) {
    int base = (it * 256 + tid) * 4;
    h4 hh;
#pragma unroll
    for (int e = 0; e < 4; ++e) hh[e] = (_Float16)(vals[it * 4 + e] * inv);
    *(h4*)(op + base) = hh;
  }
}

// ---------------------------------------------------------------------------
extern "C" void kernel_launch(void* const* d_in, const int* in_sizes, int n_in,
                              void* d_out, int out_size, void* d_ws,
                              size_t ws_size, hipStream_t stream)
{
  (void)in_sizes; (void)n_in; (void)out_size; (void)ws_size;
  const float* x   = (const float*)d_in[0];  // [4096,2048]
  const float* Wq  = (const float*)d_in[1];  // [2048,2048]
  const float* Wk  = (const float*)d_in[2];
  const float* Wv  = (const float*)d_in[3];
  const float* bch = (const float*)d_in[4];  // [4096,2048]
  const float* bt0 = (const float*)d_in[5];  // b_t[0]
  float* out = (float*)d_out;

  char* ws = (char*)d_ws;
  // Phase A: [0,67.1M) = xhi,xlo,wqkh,wqkl ; wvh ; vT ; qkh ; qkl
  // Phase B: S (67.1M) aliases [0,67.1M) after step 4; attn aliases qkh.
  const size_t O_XHI  = 0;                    // 16.8M, dead after vT gemm
  const size_t O_XLO  = 16777216;             // 16.8M
  const size_t O_WQKH = 33554432;             // 16.8M ([Wq|Wk]^T hi)
  const size_t O_WQKL = 50331648;             // 16.8M, region ends 67108864
  const size_t O_WVH  = 67108864;             //  8.4M, dead after vT gemm
  const size_t O_VT   = 75497472;             // 16.8M, live to end
  const size_t O_QKH  = 92274688;             // 33.55M (q|k hi, ld 4096)
  const size_t O_QKL  = 125829120;            // 33.55M, ends 159383552
  const size_t O_S    = 0;                    // 67.1M fp32 (alias phase A)
  const size_t O_ATTN = O_QKH;                // 33.55M fp16 (alias dead q|k)

  _Float16* xhi  = (_Float16*)(ws + O_XHI);
  _Float16* xlo  = (_Float16*)(ws + O_XLO);
  _Float16* wqkh = (_Float16*)(ws + O_WQKH);
  _Float16* wqkl = (_Float16*)(ws + O_WQKL);
  _Float16* wvh  = (_Float16*)(ws + O_WVH);
  _Float16* vT   = (_Float16*)(ws + O_VT);
  _Float16* qkh  = (_Float16*)(ws + O_QKH);
  _Float16* qkl  = (_Float16*)(ws + O_QKL);
  float*    S    = (float*)(ws + O_S);
  _Float16* attn = (_Float16*)(ws + O_ATTN);

  // 1) split x
  split_x_kernel<<<2097152 / 256, 256, 0, stream>>>(x, xhi, xlo, 2097152);
  // 2) transpose+split weights; Wq and Wk stacked -> B = [Wq|Wk]^T (4096 rows)
  dim3 tg(64, 64);
  transpose_split_w<<<tg, 256, 0, stream>>>(Wq, wqkh, wqkl, 2048, 1);
  transpose_split_w<<<tg, 256, 0, stream>>>(Wk, wqkh + 4194304, wqkl + 4194304, 2048, 1);
  transpose_split_w<<<tg, 256, 0, stream>>>(Wv, wvh, nullptr, 2048, 0);

  // 3) [q|k] = x @ [Wq|Wk]  (split, fused, hi/lo out, ldc=4096)
  dim3 gqk(4096 / 128, 4096 / 128);
  gemm_bt<EPI_QK, true><<<gqk, 256, 0, stream>>>(
      xhi, xlo, wqkh, wqkl, 2048, 2048, 2048, 4096, 0,
      nullptr, qkh, qkl, nullptr, nullptr);
  // 4) vT = (x@Wv)^T  (plain fp16, transposed write)
  dim3 gv(2048 / 128, 4096 / 128);
  gemm_bt<EPI_VT, false><<<gv, 256, 0, stream>>>(
      xhi, nullptr, wvh, nullptr, 2048, 2048, 2048, 0, 4096,
      nullptr, vT, nullptr, nullptr, nullptr);

  // 5) S = q@k^T (split; q = qk cols 0..2047, k = cols 2048..4095)
  dim3 gs(4096 / 128, 4096 / 128);
  gemm_bt<EPI_S, true><<<gs, 256, 0, stream>>>(
      qkh, qkl, qkh + 2048, qkl + 2048, 2048, 4096, 4096, 4096, 0,
      S, nullptr, nullptr, nullptr, nullptr);

  // 6) softmax((S + chan_bias)/sqrt(d)) -> dense fp16 attn
  softmax_bias_kernel<<<4096, 256, 0, stream>>>(S, attn, 4096);

  // 7) out = attn@v + b_channel + b_t[0] + PE(0)
  dim3 gc(2048 / 128, 4096 / 128);
  gemm_bt<EPI_CTX, false><<<gc, 256, 0, stream>>>(
      attn, nullptr, vT, nullptr, 4096, 4096, 4096, 2048, 0,
      out, nullptr, nullptr, bch, bt0);
}